// Round 1
// baseline (357.353 us; speedup 1.0000x reference)
//
#include <hip/hip_runtime.h>

typedef unsigned short ushort_t;
typedef unsigned int uint32;
typedef __bf16 bf16x8 __attribute__((ext_vector_type(8)));
typedef float f32x4 __attribute__((ext_vector_type(4)));

#define NTOK 128
#define DIMX 180
#define NH 6
#define HD 30
#define KP 192      // padded K (180->192)
#define NQKV 576    // padded qkv out cols: 3*6*32
#define NWIN 64

__device__ __forceinline__ ushort_t f2bf(float f){
  uint32 u = __float_as_uint(f);
  u += 0x7FFFu + ((u >> 16) & 1u);
  return (ushort_t)(u >> 16);
}
__device__ __forceinline__ float bf2f(ushort_t h){
  return __uint_as_float(((uint32)h) << 16);
}
__device__ __forceinline__ f32x4 mfma16(bf16x8 a, bf16x8 b, f32x4 c){
  return __builtin_amdgcn_mfma_f32_16x16x32_bf16(a, b, c, 0, 0, 0);
}

// ---------------- prep kernels ----------------

// wqkvT[oc'][k], oc' = (sel*6+head)*32 + d (d padded to 32), k padded to 192
__global__ void prep_wqkv(const float* __restrict__ w, ushort_t* __restrict__ o){
  int oc = blockIdx.x, k = threadIdx.x;
  int seg = oc >> 5, d = oc & 31;
  int sel = seg / 6, head = seg % 6;
  float v = 0.f;
  if (d < HD && k < DIMX) v = w[k*(3*DIMX) + sel*DIMX + head*HD + d];
  o[oc*KP + k] = f2bf(v);
}

__global__ void prep_wfc(const float* __restrict__ w, ushort_t* __restrict__ o){
  int oc = blockIdx.x, k = threadIdx.x;
  float v = (oc < DIMX && k < DIMX) ? w[k*DIMX + oc] : 0.f;
  o[oc*KP + k] = f2bf(v);
}

// bias16[(w*6+h)][n][m] = rpt[rpi[n,m]][h] + mask[w][n][m]
__global__ void prep_bias(const float* __restrict__ rpt, const float* __restrict__ mask,
                          const int* __restrict__ rpi, ushort_t* __restrict__ o){
  int idx = blockIdx.x;           // (w*6+h)*128 + n
  int m = threadIdx.x;
  int n = idx & 127;
  int t = idx >> 7;               // w*6+h
  int h = t % NH, w = t / NH;
  float v = rpt[rpi[n*NTOK + m]*NH + h] + mask[((size_t)w*NTOK + n)*NTOK + m];
  o[(size_t)idx*NTOK + m] = f2bf(v);
}

// ---------------- QKV projection ----------------
// grid 2048: block = 64 rows of (b,n). 8 waves: 2M x 4N, wave tile 32x144.
__global__ __launch_bounds__(512) void qkv_kernel(
    const float* __restrict__ x, const ushort_t* __restrict__ wqkvT,
    const float* __restrict__ b_qkv,
    ushort_t* __restrict__ Qo, ushort_t* __restrict__ Ko, ushort_t* __restrict__ Vo)
{
  __shared__ ushort_t xs[64*200];      // [64][200] bf16, 2-way-conflict stride
  const int tid = threadIdx.x;
  const float* xb = x + (size_t)blockIdx.x * 64 * DIMX;

  // stage 64x180 fp32 -> bf16 LDS (pad cols 180..191 = 0)
  for (int c = tid; c < 64*45; c += 512){
    int row = c / 45, c4 = (c % 45) * 4;
    float4 f = reinterpret_cast<const float4*>(xb)[c];
    uint32 lo = ((uint32)f2bf(f.y) << 16) | f2bf(f.x);
    uint32 hi = ((uint32)f2bf(f.w) << 16) | f2bf(f.z);
    *reinterpret_cast<uint2*>(&xs[row*200 + c4]) = make_uint2(lo, hi);
  }
  for (int c = tid; c < 64*12; c += 512){
    xs[(c/12)*200 + 180 + (c%12)] = 0;
  }
  __syncthreads();

  const int wave = tid >> 6, lane = tid & 63;
  const int wm = wave >> 2, wn = wave & 3;
  const int l16 = lane & 15, lq = lane >> 4;

  f32x4 acc[2][9];
  #pragma unroll
  for (int i = 0; i < 2; i++)
    #pragma unroll
    for (int j = 0; j < 9; j++) acc[i][j] = f32x4{0.f,0.f,0.f,0.f};

  #pragma unroll
  for (int ks = 0; ks < 6; ks++){
    const int k0 = ks*32 + lq*8;
    bf16x8 a0 = *reinterpret_cast<const bf16x8*>(&xs[(wm*32 +      l16)*200 + k0]);
    bf16x8 a1 = *reinterpret_cast<const bf16x8*>(&xs[(wm*32 + 16 + l16)*200 + k0]);
    #pragma unroll
    for (int ct = 0; ct < 9; ct++){
      const int oc = (wn*9 + ct)*16 + l16;
      bf16x8 bf = *reinterpret_cast<const bf16x8*>(wqkvT + (size_t)oc*KP + k0);
      acc[0][ct] = mfma16(a0, bf, acc[0][ct]);
      acc[1][ct] = mfma16(a1, bf, acc[1][ct]);
    }
  }

  const int b = blockIdx.x >> 1;
  const int rwin0 = (blockIdx.x & 1) * 64 + wm*32;
  const float scale = 0.18257418583505536f;   // 1/sqrt(30)
  #pragma unroll
  for (int ct = 0; ct < 9; ct++){
    const int gt = wn*9 + ct;
    const int seg = gt >> 1;
    const int d = (gt & 1)*16 + l16;           // 0..31
    const int sel = seg / NH, head = seg % NH;
    float bias = 0.f;
    if (d < HD) bias = b_qkv[sel*DIMX + head*HD + d];
    #pragma unroll
    for (int rt = 0; rt < 2; rt++){
      #pragma unroll
      for (int r = 0; r < 4; r++){
        const int row = rwin0 + rt*16 + lq*4 + r;
        float v = acc[rt][ct][r];
        if (d < HD) v += bias;                 // padded cols stay exactly 0
        if (sel == 0) v *= scale;
        ushort_t hv = f2bf(v);
        if (sel == 0)      Qo[(((size_t)b*NH + head)*NTOK + row)*32 + d] = hv;
        else if (sel == 1) Ko[(((size_t)b*NH + head)*NTOK + row)*32 + d] = hv;
        else               Vo[(((size_t)b*NH + head)*32 + d)*NTOK + row] = hv;
      }
    }
  }
}

// ---------------- fused attention + FC ----------------
// grid 1024 (one window), 8 waves x 16 q-rows.
__global__ __launch_bounds__(512) void attn_fc_kernel(
    const ushort_t* __restrict__ Qo, const ushort_t* __restrict__ Ko, const ushort_t* __restrict__ Vo,
    const ushort_t* __restrict__ bias16, const ushort_t* __restrict__ wfcT,
    const float* __restrict__ b_fc, float* __restrict__ out)
{
  __shared__ ushort_t smem[52480];
  ushort_t* ao_s = smem;              // [128][200]  attention output (bf16)
  ushort_t* k_s  = smem + 25600;      // [128][40]
  ushort_t* v_s  = smem + 30720;      // [32][136]   (V^T)
  ushort_t* p_s  = smem + 35072;      // [8][16][136]
  ushort_t* wf_s = smem + 25600;      // [192][104]  (aliases k/v/p after attention)

  const int tid = threadIdx.x;
  const int b = blockIdx.x;
  const int wk = b & (NWIN-1);
  const int wave = tid >> 6, lane = tid & 63;
  const int l16 = lane & 15, lq = lane >> 4;
  const int wbase = wave * 16;

  // zero FC K-padding cols of attention-output tile
  for (int c = tid; c < 128*12; c += 512)
    ao_s[(c/12)*200 + 180 + (c%12)] = 0;

  for (int h = 0; h < NH; h++){
    __syncthreads();
    // stage K [128][32] -> k_s[128][40]
    {
      const ushort_t* kg = Ko + (((size_t)b*NH + h)*NTOK)*32;
      int row = tid >> 2, part = tid & 3;
      *reinterpret_cast<bf16x8*>(&k_s[row*40 + part*8]) =
        *reinterpret_cast<const bf16x8*>(kg + row*32 + part*8);
    }
    // stage V^T [32][128] -> v_s[32][136]
    {
      const ushort_t* vg = Vo + (((size_t)b*NH + h)*32)*NTOK;
      int row = tid >> 4, part = tid & 15;
      *reinterpret_cast<bf16x8*>(&v_s[row*136 + part*8]) =
        *reinterpret_cast<const bf16x8*>(vg + row*NTOK + part*8);
    }
    __syncthreads();

    // QK^T: this wave's 16 q-rows x 128 tokens  (scale folded into Q)
    bf16x8 aq = *reinterpret_cast<const bf16x8*>(
        Qo + (((size_t)b*NH + h)*NTOK + wbase + l16)*32 + lq*8);
    f32x4 acc[8];
    #pragma unroll
    for (int t = 0; t < 8; t++){
      bf16x8 bk = *reinterpret_cast<const bf16x8*>(&k_s[(t*16 + l16)*40 + lq*8]);
      acc[t] = mfma16(aq, bk, f32x4{0.f,0.f,0.f,0.f});
    }
    // + bias (rpe+mask)
    const ushort_t* bp = bias16 + (((size_t)(wk*NH + h)*NTOK) + wbase + lq*4)*NTOK + l16;
    #pragma unroll
    for (int t = 0; t < 8; t++)
      #pragma unroll
      for (int r = 0; r < 4; r++)
        acc[t][r] += bf2f(bp[r*NTOK + t*16]);

    // softmax per row (row = wbase + lq*4 + r; cols spread over l16 x t)
    #pragma unroll
    for (int r = 0; r < 4; r++){
      float m = acc[0][r];
      #pragma unroll
      for (int t = 1; t < 8; t++) m = fmaxf(m, acc[t][r]);
      #pragma unroll
      for (int off = 1; off < 16; off <<= 1) m = fmaxf(m, __shfl_xor(m, off));
      float s = 0.f;
      #pragma unroll
      for (int t = 0; t < 8; t++){
        float e = __expf(acc[t][r] - m);
        acc[t][r] = e;
        s += e;
      }
      #pragma unroll
      for (int off = 1; off < 16; off <<= 1) s += __shfl_xor(s, off);
      float inv = 1.0f / s;
      ushort_t* pr = p_s + wave*2176 + (lq*4 + r)*136 + l16;
      #pragma unroll
      for (int t = 0; t < 8; t++)
        pr[t*16] = f2bf(acc[t][r] * inv);
    }
    __syncthreads();

    // PV: out[16 x 32] = P[16 x 128] @ V[128 x 32]
    f32x4 po[2] = { f32x4{0.f,0.f,0.f,0.f}, f32x4{0.f,0.f,0.f,0.f} };
    #pragma unroll
    for (int ks = 0; ks < 4; ks++){
      const int k0 = ks*32 + lq*8;
      bf16x8 ap = *reinterpret_cast<const bf16x8*>(&p_s[wave*2176 + l16*136 + k0]);
      #pragma unroll
      for (int ct = 0; ct < 2; ct++){
        bf16x8 bv = *reinterpret_cast<const bf16x8*>(&v_s[(ct*16 + l16)*136 + k0]);
        po[ct] = mfma16(ap, bv, po[ct]);
      }
    }
    #pragma unroll
    for (int ct = 0; ct < 2; ct++){
      const int d = ct*16 + l16;
      if (d < HD){
        #pragma unroll
        for (int r = 0; r < 4; r++)
          ao_s[(wbase + lq*4 + r)*200 + h*HD + d] = f2bf(po[ct][r]);
      }
    }
  }

  // FC: out[b] = ao @ w_fc + b_fc   (per wave: 16 rows x 192 cols, K=192)
  f32x4 acc2[12];
  #pragma unroll
  for (int j = 0; j < 12; j++) acc2[j] = f32x4{0.f,0.f,0.f,0.f};

  #pragma unroll
  for (int ph = 0; ph < 2; ph++){
    __syncthreads();
    for (int c = tid; c < 2304; c += 512){   // stage wfcT[:, ph*96 : +96]
      int row = c / 12, part = c % 12;
      *reinterpret_cast<bf16x8*>(&wf_s[row*104 + part*8]) =
        *reinterpret_cast<const bf16x8*>(wfcT + (size_t)row*KP + ph*96 + part*8);
    }
    __syncthreads();
    #pragma unroll
    for (int k3 = 0; k3 < 3; k3++){
      const int kl = k3*32 + lq*8;
      bf16x8 af = *reinterpret_cast<const bf16x8*>(&ao_s[(wbase + l16)*200 + ph*96 + kl]);
      #pragma unroll
      for (int ct = 0; ct < 12; ct++){
        bf16x8 bw = *reinterpret_cast<const bf16x8*>(&wf_s[(ct*16 + l16)*104 + kl]);
        acc2[ct] = mfma16(af, bw, acc2[ct]);
      }
    }
  }

  #pragma unroll
  for (int ct = 0; ct < 12; ct++){
    const int col = ct*16 + l16;
    if (col < DIMX){
      const float bb = b_fc[col];
      #pragma unroll
      for (int r = 0; r < 4; r++){
        const int row = wbase + lq*4 + r;
        out[((size_t)b*NTOK + row)*DIMX + col] = acc2[ct][r] + bb;
      }
    }
  }
}

// ---------------- launch ----------------
extern "C" void kernel_launch(void* const* d_in, const int* in_sizes, int n_in,
                              void* d_out, int out_size, void* d_ws, size_t ws_size,
                              hipStream_t stream)
{
  const float* x      = (const float*)d_in[0];
  const float* w_qkv  = (const float*)d_in[1];
  const float* b_qkv  = (const float*)d_in[2];
  const float* w_fc   = (const float*)d_in[3];
  const float* b_fc   = (const float*)d_in[4];
  const float* rpt    = (const float*)d_in[5];
  const float* mask   = (const float*)d_in[6];
  const int*   rpi    = (const int*)d_in[7];
  float* out = (float*)d_out;

  char* ws = (char*)d_ws;
  // layout (bytes):
  //   0         wqkvT   576*192*2 = 221184
  //   221184    wfcT    192*192*2 = 73728
  //   294912    bias16  64*6*128*128*2 = 12582912
  //   12877824  Qo      1024*6*128*32*2 = 50331648
  //   63209472  Ko      50331648
  //   113541120 Vo      50331648   -> total 163872768
  if (ws_size < (size_t)163872768) return;
  ushort_t* wqkvT  = (ushort_t*)(ws);
  ushort_t* wfcT   = (ushort_t*)(ws + 221184);
  ushort_t* bias16 = (ushort_t*)(ws + 294912);
  ushort_t* Qo     = (ushort_t*)(ws + 12877824);
  ushort_t* Ko     = (ushort_t*)(ws + 63209472);
  ushort_t* Vo     = (ushort_t*)(ws + 113541120);

  hipLaunchKernelGGL(prep_wqkv, dim3(NQKV), dim3(KP), 0, stream, w_qkv, wqkvT);
  hipLaunchKernelGGL(prep_wfc,  dim3(KP),   dim3(KP), 0, stream, w_fc, wfcT);
  hipLaunchKernelGGL(prep_bias, dim3(NWIN*NH*NTOK), dim3(NTOK), 0, stream, rpt, mask, rpi, bias16);
  hipLaunchKernelGGL(qkv_kernel, dim3(2048), dim3(512), 0, stream, x, wqkvT, b_qkv, Qo, Ko, Vo);
  hipLaunchKernelGGL(attn_fc_kernel, dim3(1024), dim3(512), 0, stream,
                     Qo, Ko, Vo, bias16, wfcT, b_fc, out);
}

// Round 2
// 354.348 us; speedup vs baseline: 1.0085x; 1.0085x over previous
//
#include <hip/hip_runtime.h>

typedef unsigned short ushort_t;
typedef unsigned int uint32;
typedef __bf16 bf16x8 __attribute__((ext_vector_type(8)));
typedef float f32x4 __attribute__((ext_vector_type(4)));

#define NTOK 128
#define DIMX 180
#define NH 6
#define HD 30
#define KP 192      // padded K (180->192)
#define NQKV 576
#define NWIN 64

__device__ __forceinline__ ushort_t f2bf(float f){
  uint32 u = __float_as_uint(f);
  u += 0x7FFFu + ((u >> 16) & 1u);
  return (ushort_t)(u >> 16);
}
__device__ __forceinline__ float bf2f(ushort_t h){
  return __uint_as_float(((uint32)h) << 16);
}
__device__ __forceinline__ f32x4 mfma16(bf16x8 a, bf16x8 b, f32x4 c){
  return __builtin_amdgcn_mfma_f32_16x16x32_bf16(a, b, c, 0, 0, 0);
}

// ---------------- prep kernels ----------------

// wqkvT[oc'][k], oc' = (sel*6+head)*32 + d (d padded to 32), k padded to 192
__global__ void prep_wqkv(const float* __restrict__ w, ushort_t* __restrict__ o){
  int oc = blockIdx.x, k = threadIdx.x;
  int seg = oc >> 5, d = oc & 31;
  int sel = seg / 6, head = seg % 6;
  float v = 0.f;
  if (d < HD && k < DIMX) v = w[k*(3*DIMX) + sel*DIMX + head*HD + d];
  o[oc*KP + k] = f2bf(v);
}

__global__ void prep_wfc(const float* __restrict__ w, ushort_t* __restrict__ o){
  int oc = blockIdx.x, k = threadIdx.x;
  float v = (oc < DIMX && k < DIMX) ? w[k*DIMX + oc] : 0.f;
  o[oc*KP + k] = f2bf(v);
}

// bias16[(w*6+h)][n][m] = rpt[rpi[n,m]][h] + mask[w][n][m]
__global__ void prep_bias(const float* __restrict__ rpt, const float* __restrict__ mask,
                          const int* __restrict__ rpi, ushort_t* __restrict__ o){
  int idx = blockIdx.x;           // (w*6+h)*128 + n
  int m = threadIdx.x;
  int n = idx & 127;
  int t = idx >> 7;               // w*6+h
  int h = t % NH, w = t / NH;
  float v = rpt[rpi[n*NTOK + m]*NH + h] + mask[((size_t)w*NTOK + n)*NTOK + m];
  o[(size_t)idx*NTOK + m] = f2bf(v);
}

// ---------------- fully fused: QKV + attention + FC ----------------
// grid 1024 (one window per block), 8 waves x 16 q-rows each.
// Dynamic LDS layout (ushort units):
//   xs   @     0  [128][200]  x in bf16 (cols 180..191 zero)
//   ao_s @ 25600  [128][200]  attention output accum (bf16)
//   q_s  @ 51200  [128][40]
//   k_s  @ 56320  [128][40]
//   v_s  @ 61440  [32][136]   V^T
//   p_s  @ 65792  8 x [16][72]  per-wave P half-buffer
//   wf_s @ 51200  [192][104]  (aliases q/k/v/p during FC)
// total 75008 ushorts = 150016 B
__global__ __launch_bounds__(512, 2) void fused_kernel(
    const float* __restrict__ x, const ushort_t* __restrict__ wqkvT,
    const float* __restrict__ b_qkv, const ushort_t* __restrict__ bias16,
    const ushort_t* __restrict__ wfcT, const float* __restrict__ b_fc,
    float* __restrict__ out)
{
  extern __shared__ ushort_t smem[];
  ushort_t* xs   = smem;
  ushort_t* ao_s = smem + 25600;
  ushort_t* q_s  = smem + 51200;
  ushort_t* k_s  = smem + 56320;
  ushort_t* v_s  = smem + 61440;
  ushort_t* p_s  = smem + 65792;
  ushort_t* wf_s = smem + 51200;

  const int tid = threadIdx.x;
  const int b = blockIdx.x;
  const int wk = b & (NWIN-1);
  const int wave = tid >> 6, lane = tid & 63;
  const int l16 = lane & 15, lq = lane >> 4;
  const int wbase = wave * 16;

  // stage x: 128 x 180 fp32 -> bf16 [128][200]
  const float* xb = x + (size_t)b * NTOK * DIMX;
  for (int c = tid; c < NTOK*45; c += 512){
    int row = c / 45, c4 = (c % 45) * 4;
    float4 f = reinterpret_cast<const float4*>(xb)[c];
    uint32 lo = ((uint32)f2bf(f.y) << 16) | f2bf(f.x);
    uint32 hi = ((uint32)f2bf(f.w) << 16) | f2bf(f.z);
    *reinterpret_cast<uint2*>(&xs[row*200 + c4]) = make_uint2(lo, hi);
  }
  for (int c = tid; c < NTOK*12; c += 512){
    int row = c / 12, cc = 180 + (c % 12);
    xs[row*200 + cc] = 0;
    ao_s[row*200 + cc] = 0;
  }

  const float scale = 0.18257418583505536f;   // 1/sqrt(30)

  for (int h = 0; h < NH; h++){
    __syncthreads();   // xs ready / prev head's k_s,v_s reads done

    // ---- QKV projection for head h: this wave's 16 rows x 96 cols ----
    f32x4 acc[6];
    #pragma unroll
    for (int j = 0; j < 6; j++) acc[j] = f32x4{0.f,0.f,0.f,0.f};
    #pragma unroll
    for (int ks = 0; ks < 6; ks++){
      const int k0 = ks*32 + lq*8;
      bf16x8 a = *reinterpret_cast<const bf16x8*>(&xs[(wbase + l16)*200 + k0]);
      #pragma unroll
      for (int j = 0; j < 6; j++){
        const int oc = ((j>>1)*NH + h)*32 + (j&1)*16 + l16;
        bf16x8 bw = *reinterpret_cast<const bf16x8*>(wqkvT + (size_t)oc*KP + k0);
        acc[j] = mfma16(a, bw, acc[j]);
      }
    }
    #pragma unroll
    for (int j = 0; j < 6; j++){
      const int sel = j >> 1;
      const int d = (j&1)*16 + l16;          // 0..31 (pad cols give exact 0)
      float bias = (d < HD) ? b_qkv[sel*DIMX + h*HD + d] : 0.f;
      #pragma unroll
      for (int r = 0; r < 4; r++){
        const int row = wbase + lq*4 + r;
        float v = acc[j][r] + bias;
        if (sel == 0)      q_s[row*40 + d] = f2bf(v * scale);
        else if (sel == 1) k_s[row*40 + d] = f2bf(v);
        else               v_s[d*136 + row] = f2bf(v);
      }
    }
    __syncthreads();   // k_s, v_s visible to all waves

    // ---- QK^T: 16 q-rows x 128 tokens (scale folded into Q) ----
    bf16x8 aq = *reinterpret_cast<const bf16x8*>(&q_s[(wbase + l16)*40 + lq*8]);
    f32x4 s[8];
    #pragma unroll
    for (int t = 0; t < 8; t++){
      bf16x8 bk = *reinterpret_cast<const bf16x8*>(&k_s[(t*16 + l16)*40 + lq*8]);
      s[t] = mfma16(aq, bk, f32x4{0.f,0.f,0.f,0.f});
    }
    // + rpe+mask bias
    const ushort_t* bp = bias16 + ((size_t)(wk*NH + h)*NTOK + wbase + lq*4)*NTOK + l16;
    #pragma unroll
    for (int t = 0; t < 8; t++)
      #pragma unroll
      for (int r = 0; r < 4; r++)
        s[t][r] += bf2f(bp[r*NTOK + t*16]);

    // softmax per row (row local = lq*4+r; cols spread over l16 x t)
    #pragma unroll
    for (int r = 0; r < 4; r++){
      float m = s[0][r];
      #pragma unroll
      for (int t = 1; t < 8; t++) m = fmaxf(m, s[t][r]);
      #pragma unroll
      for (int off = 1; off < 16; off <<= 1) m = fmaxf(m, __shfl_xor(m, off));
      float sum = 0.f;
      #pragma unroll
      for (int t = 0; t < 8; t++){
        float e = __expf(s[t][r] - m);
        s[t][r] = e; sum += e;
      }
      #pragma unroll
      for (int off = 1; off < 16; off <<= 1) sum += __shfl_xor(sum, off);
      float inv = 1.0f / sum;
      #pragma unroll
      for (int t = 0; t < 8; t++) s[t][r] *= inv;
    }

    // ---- PV via per-wave P buffer, two k-halves of 64 ----
    f32x4 po[2] = { f32x4{0.f,0.f,0.f,0.f}, f32x4{0.f,0.f,0.f,0.f} };
    ushort_t* pw = p_s + wave*1152;   // [16][72]
    #pragma unroll
    for (int half = 0; half < 2; half++){
      #pragma unroll
      for (int r = 0; r < 4; r++)
        #pragma unroll
        for (int t = 0; t < 4; t++)
          pw[(lq*4 + r)*72 + t*16 + l16] = f2bf(s[half*4 + t][r]);
      #pragma unroll
      for (int ks = 0; ks < 2; ks++){
        const int kk = ks*32 + lq*8;
        bf16x8 ap = *reinterpret_cast<const bf16x8*>(&pw[l16*72 + kk]);
        #pragma unroll
        for (int ct = 0; ct < 2; ct++){
          bf16x8 bv = *reinterpret_cast<const bf16x8*>(&v_s[(ct*16 + l16)*136 + half*64 + kk]);
          po[ct] = mfma16(ap, bv, po[ct]);
        }
      }
    }
    #pragma unroll
    for (int ct = 0; ct < 2; ct++){
      const int d = ct*16 + l16;
      if (d < HD){
        #pragma unroll
        for (int r = 0; r < 4; r++)
          ao_s[(wbase + lq*4 + r)*200 + h*HD + d] = f2bf(po[ct][r]);
      }
    }
  }

  // ---- FC: out = ao @ w_fc + b_fc (per wave: 16 rows x 192 cols, K=192) ----
  f32x4 acc2[12];
  #pragma unroll
  for (int j = 0; j < 12; j++) acc2[j] = f32x4{0.f,0.f,0.f,0.f};

  #pragma unroll
  for (int ph = 0; ph < 2; ph++){
    __syncthreads();   // prior reads of aliased region done
    for (int c = tid; c < 2304; c += 512){   // stage wfcT[:, ph*96 : +96]
      int row = c / 12, part = c % 12;
      *reinterpret_cast<bf16x8*>(&wf_s[row*104 + part*8]) =
        *reinterpret_cast<const bf16x8*>(wfcT + (size_t)row*KP + ph*96 + part*8);
    }
    __syncthreads();
    #pragma unroll
    for (int k3 = 0; k3 < 3; k3++){
      const int kl = k3*32 + lq*8;
      bf16x8 af = *reinterpret_cast<const bf16x8*>(&ao_s[(wbase + l16)*200 + ph*96 + kl]);
      #pragma unroll
      for (int ct = 0; ct < 12; ct++){
        bf16x8 bw = *reinterpret_cast<const bf16x8*>(&wf_s[(ct*16 + l16)*104 + kl]);
        acc2[ct] = mfma16(af, bw, acc2[ct]);
      }
    }
  }

  #pragma unroll
  for (int ct = 0; ct < 12; ct++){
    const int col = ct*16 + l16;
    if (col < DIMX){
      const float bb = b_fc[col];
      #pragma unroll
      for (int r = 0; r < 4; r++){
        const int row = wbase + lq*4 + r;
        out[((size_t)b*NTOK + row)*DIMX + col] = acc2[ct][r] + bb;
      }
    }
  }
}

// ---------------- launch ----------------
extern "C" void kernel_launch(void* const* d_in, const int* in_sizes, int n_in,
                              void* d_out, int out_size, void* d_ws, size_t ws_size,
                              hipStream_t stream)
{
  const float* x      = (const float*)d_in[0];
  const float* w_qkv  = (const float*)d_in[1];
  const float* b_qkv  = (const float*)d_in[2];
  const float* w_fc   = (const float*)d_in[3];
  const float* b_fc   = (const float*)d_in[4];
  const float* rpt    = (const float*)d_in[5];
  const float* mask   = (const float*)d_in[6];
  const int*   rpi    = (const int*)d_in[7];
  float* out = (float*)d_out;

  char* ws = (char*)d_ws;
  // ws layout: wqkvT 221184 B @0, wfcT 73728 B @221184, bias16 12582912 B @294912
  if (ws_size < (size_t)12877824) return;
  ushort_t* wqkvT  = (ushort_t*)(ws);
  ushort_t* wfcT   = (ushort_t*)(ws + 221184);
  ushort_t* bias16 = (ushort_t*)(ws + 294912);

  hipLaunchKernelGGL(prep_wqkv, dim3(NQKV), dim3(KP), 0, stream, w_qkv, wqkvT);
  hipLaunchKernelGGL(prep_wfc,  dim3(KP),   dim3(KP), 0, stream, w_fc, wfcT);
  hipLaunchKernelGGL(prep_bias, dim3(NWIN*NH*NTOK), dim3(NTOK), 0, stream, rpt, mask, rpi, bias16);

  (void)hipFuncSetAttribute((const void*)fused_kernel,
                            hipFuncAttributeMaxDynamicSharedMemorySize, 150016);
  hipLaunchKernelGGL(fused_kernel, dim3(1024), dim3(512), 150016, stream,
                     x, wqkvT, b_qkv, bias16, wfcT, b_fc, out);
}

// Round 3
// 340.604 us; speedup vs baseline: 1.0492x; 1.0404x over previous
//
#include <hip/hip_runtime.h>

typedef unsigned short ushort_t;
typedef unsigned int uint32;
typedef __bf16 bf16x8 __attribute__((ext_vector_type(8)));
typedef float f32x4 __attribute__((ext_vector_type(4)));

#define NTOK 128
#define DIMX 180
#define NH 6
#define HD 30
#define KP 192      // padded K (180->192)
#define NQKV 576
#define NWIN 64

__device__ __forceinline__ ushort_t f2bf(float f){
  uint32 u = __float_as_uint(f);
  u += 0x7FFFu + ((u >> 16) & 1u);
  return (ushort_t)(u >> 16);
}
__device__ __forceinline__ float bf2f(ushort_t h){
  return __uint_as_float(((uint32)h) << 16);
}
__device__ __forceinline__ f32x4 mfma16(bf16x8 a, bf16x8 b, f32x4 c){
  return __builtin_amdgcn_mfma_f32_16x16x32_bf16(a, b, c, 0, 0, 0);
}

// ---------------- prep kernels ----------------

// wqkvT[oc'][k], oc' = (sel*6+head)*32 + d (d padded to 32), k padded to 192
__global__ void prep_wqkv(const float* __restrict__ w, ushort_t* __restrict__ o){
  int oc = blockIdx.x, k = threadIdx.x;
  int seg = oc >> 5, d = oc & 31;
  int sel = seg / 6, head = seg % 6;
  float v = 0.f;
  if (d < HD && k < DIMX) v = w[k*(3*DIMX) + sel*DIMX + head*HD + d];
  o[oc*KP + k] = f2bf(v);
}

__global__ void prep_wfc(const float* __restrict__ w, ushort_t* __restrict__ o){
  int oc = blockIdx.x, k = threadIdx.x;
  float v = (oc < DIMX && k < DIMX) ? w[k*DIMX + oc] : 0.f;
  o[oc*KP + k] = f2bf(v);
}

// bias_p in MFMA C-fragment order:
//   bias_p[(((w*6+h)*8 + wave)*64 + lane)*32 + t*4 + r]
//     = rpt[rpi[n,m],h] + mask[w,n,m],  n = wave*16 + (lane>>4)*4 + r, m = t*16 + (lane&15)
__global__ void prep_bias(const float* __restrict__ rpt, const float* __restrict__ mask,
                          const int* __restrict__ rpi, ushort_t* __restrict__ o){
  int blk = blockIdx.x;            // (w*6+h)*8 + wave
  int wave = blk & 7, wh = blk >> 3;
  int h = wh % NH, w = wh / NH;
  int i = threadIdx.x;             // 512
  int lane = i >> 3, t = i & 7;
  int l16 = lane & 15, lq = lane >> 4;
  int m = t*16 + l16;
  ushort_t vals[4];
  #pragma unroll
  for (int r = 0; r < 4; r++){
    int n = wave*16 + lq*4 + r;
    float v = rpt[rpi[n*NTOK + m]*NH + h] + mask[((size_t)w*NTOK + n)*NTOK + m];
    vals[r] = f2bf(v);
  }
  *reinterpret_cast<uint2*>(&o[((size_t)blk*64 + lane)*32 + t*4]) =
      *reinterpret_cast<const uint2*>(vals);
}

// ---------------- QKV projection ----------------
// grid 2048: block = 64 rows. 8 waves: 2M x 4N, wave tile 32x144. K=192.
// LDS (ushort units, aliased):
//   phase A: xs  [64][200] = 12800 @ 0
//   phase B: cqk [64][392] = 25088 @ 0      (Q,K cols 0..383)
//            cv  [192][72] = 13824 @ 25088  (V transposed)
//   total 38912 ush = 77824 B  -> 2 blocks/CU
__global__ __launch_bounds__(512, 4) void qkv_kernel(
    const float* __restrict__ x, const ushort_t* __restrict__ wqkvT,
    const float* __restrict__ b_qkv,
    ushort_t* __restrict__ Qo, ushort_t* __restrict__ Ko, ushort_t* __restrict__ Vo)
{
  extern __shared__ ushort_t sm1[];
  ushort_t* xs  = sm1;
  ushort_t* cqk = sm1;
  ushort_t* cv  = sm1 + 25088;

  const int tid = threadIdx.x;
  const float* xb = x + (size_t)blockIdx.x * 64 * DIMX;

  // stage 64x180 fp32 -> bf16 LDS (pad cols 180..191 = 0)
  for (int c = tid; c < 64*45; c += 512){
    int row = c / 45, c4 = (c % 45) * 4;
    float4 f = reinterpret_cast<const float4*>(xb)[c];
    uint32 lo = ((uint32)f2bf(f.y) << 16) | f2bf(f.x);
    uint32 hi = ((uint32)f2bf(f.w) << 16) | f2bf(f.z);
    *reinterpret_cast<uint2*>(&xs[row*200 + c4]) = make_uint2(lo, hi);
  }
  for (int c = tid; c < 64*12; c += 512)
    xs[(c/12)*200 + 180 + (c%12)] = 0;
  __syncthreads();

  const int wave = tid >> 6, lane = tid & 63;
  const int wm = wave >> 2, wn = wave & 3;
  const int l16 = lane & 15, lq = lane >> 4;

  f32x4 acc[2][9];
  #pragma unroll
  for (int i = 0; i < 2; i++)
    #pragma unroll
    for (int j = 0; j < 9; j++) acc[i][j] = f32x4{0.f,0.f,0.f,0.f};

  #pragma unroll
  for (int ks = 0; ks < 6; ks++){
    const int k0 = ks*32 + lq*8;
    bf16x8 a0 = *reinterpret_cast<const bf16x8*>(&xs[(wm*32 +      l16)*200 + k0]);
    bf16x8 a1 = *reinterpret_cast<const bf16x8*>(&xs[(wm*32 + 16 + l16)*200 + k0]);
    #pragma unroll
    for (int ct = 0; ct < 9; ct++){
      const int oc = (wn*9 + ct)*16 + l16;
      bf16x8 bw = *reinterpret_cast<const bf16x8*>(wqkvT + (size_t)oc*KP + k0);
      acc[0][ct] = mfma16(a0, bw, acc[0][ct]);
      acc[1][ct] = mfma16(a1, bw, acc[1][ct]);
    }
  }
  __syncthreads();   // xs dead; C staging region live

  const float scale = 0.18257418583505536f;   // 1/sqrt(30)
  #pragma unroll
  for (int ct = 0; ct < 9; ct++){
    const int gt = wn*9 + ct;           // 0..35
    const int seg = gt >> 1;            // 0..17: 0-5 Q, 6-11 K, 12-17 V
    const int d = (gt & 1)*16 + l16;    // 0..31
    const int sel = seg / NH, hh = seg % NH;
    float bias = (d < HD) ? b_qkv[sel*DIMX + hh*HD + d] : 0.f;
    #pragma unroll
    for (int rt = 0; rt < 2; rt++){
      #pragma unroll
      for (int r = 0; r < 4; r++){
        const int row = wm*32 + rt*16 + lq*4 + r;
        float v = acc[rt][ct][r];
        if (d < HD) v += bias;
        if (sel == 0) v *= scale;
        ushort_t hv = f2bf(v);
        if (sel < 2) cqk[row*392 + seg*32 + d] = hv;
        else         cv[((seg-12)*32 + d)*72 + row] = hv;
      }
    }
  }
  __syncthreads();

  // coalesced b128 stores
  const int b = blockIdx.x >> 1;
  const int half = blockIdx.x & 1;
  for (int c = tid; c < 3072; c += 512){        // Q,K: 12 segs x 64 rows x 4 chunks
    int s = c >> 8, rem = c & 255;
    int nl = rem >> 2, dc = rem & 3;
    bf16x8 vdat = *reinterpret_cast<const bf16x8*>(&cqk[nl*392 + s*32 + dc*8]);
    ushort_t* dst = (s < NH) ? Qo : Ko;
    int hh = (s < NH) ? s : s - NH;
    *reinterpret_cast<bf16x8*>(
      &dst[(((size_t)b*NH + hh)*NTOK + half*64 + nl)*32 + dc*8]) = vdat;
  }
  for (int c = tid; c < 1536; c += 512){        // V^T: 192 rows x 8 chunks
    int vr = c >> 3, nc = c & 7;
    bf16x8 vdat = *reinterpret_cast<const bf16x8*>(&cv[vr*72 + nc*8]);
    *reinterpret_cast<bf16x8*>(
      &Vo[((size_t)b*192 + vr)*NTOK + half*64 + nc*8]) = vdat;
  }
}

// ---------------- attention + FC ----------------
// grid 1024 (one window), 8 waves x 16 q-rows.
// LDS (ushort units):
//   ao_s [128][196] = 25088 @ 0
//   k_s  [128][36]  =  4608 @ 25088
//   v_s  [32][136]  =  4352 @ 29696
//   p_s  8x[16][40] =  5120 @ 34048
//   total 39168 ush = 78336 B -> 2 blocks/CU
__global__ __launch_bounds__(512, 4) void attn_kernel(
    const ushort_t* __restrict__ Qo, const ushort_t* __restrict__ Ko, const ushort_t* __restrict__ Vo,
    const ushort_t* __restrict__ bias_p, const ushort_t* __restrict__ wfcT,
    const float* __restrict__ b_fc, float* __restrict__ out)
{
  extern __shared__ ushort_t sm2[];
  ushort_t* ao_s = sm2;
  ushort_t* k_s  = sm2 + 25088;
  ushort_t* v_s  = sm2 + 29696;
  ushort_t* p_s  = sm2 + 34048;

  const int tid = threadIdx.x;
  const int b = blockIdx.x;
  const int wk = b & (NWIN-1);
  const int wave = tid >> 6, lane = tid & 63;
  const int l16 = lane & 15, lq = lane >> 4;
  const int wbase = wave * 16;

  // zero this wave's FC K-pad columns of ao
  for (int i = lane; i < 256; i += 64){
    int rr = i >> 4, cc = i & 15;
    ao_s[(wbase + rr)*196 + 180 + cc] = 0;
  }

  for (int h = 0; h < NH; h++){
    __syncthreads();   // prev head's k_s/v_s reads done
    {
      const ushort_t* kg = Ko + ((size_t)b*NH + h)*NTOK*32;
      int row = tid >> 2, part = tid & 3;
      *reinterpret_cast<bf16x8*>(&k_s[row*36 + part*8]) =
        *reinterpret_cast<const bf16x8*>(kg + row*32 + part*8);
    }
    {
      const ushort_t* vg = Vo + ((size_t)b*NH + h)*32*NTOK;
      int row = tid >> 4, part = tid & 15;
      *reinterpret_cast<bf16x8*>(&v_s[row*136 + part*8]) =
        *reinterpret_cast<const bf16x8*>(vg + row*NTOK + part*8);
    }
    __syncthreads();   // k,v visible

    // QK^T (scale folded into Q); Q fragment straight from global (L2/L3)
    bf16x8 aq = *reinterpret_cast<const bf16x8*>(
        Qo + (((size_t)b*NH + h)*NTOK + wbase + l16)*32 + lq*8);
    f32x4 s[8];
    #pragma unroll
    for (int t = 0; t < 8; t++){
      bf16x8 bk = *reinterpret_cast<const bf16x8*>(&k_s[(t*16 + l16)*36 + lq*8]);
      s[t] = mfma16(aq, bk, f32x4{0.f,0.f,0.f,0.f});
    }
    // bias: 4 coalesced b128 loads in fragment order
    {
      const ushort_t* bp = bias_p + (((size_t)(wk*NH + h)*8 + wave)*64 + lane)*32;
      #pragma unroll
      for (int c = 0; c < 4; c++){
        bf16x8 bb = *reinterpret_cast<const bf16x8*>(bp + c*8);
        #pragma unroll
        for (int r = 0; r < 4; r++){
          s[2*c][r]   += (float)bb[r];
          s[2*c+1][r] += (float)bb[4+r];
        }
      }
    }

    // softmax per row (row = wbase + lq*4 + r; cols spread over l16 x t)
    #pragma unroll
    for (int r = 0; r < 4; r++){
      float m = s[0][r];
      #pragma unroll
      for (int t = 1; t < 8; t++) m = fmaxf(m, s[t][r]);
      #pragma unroll
      for (int off = 1; off < 16; off <<= 1) m = fmaxf(m, __shfl_xor(m, off));
      float sum = 0.f;
      #pragma unroll
      for (int t = 0; t < 8; t++){
        float e = __expf(s[t][r] - m);
        s[t][r] = e; sum += e;
      }
      #pragma unroll
      for (int off = 1; off < 16; off <<= 1) sum += __shfl_xor(sum, off);
      float inv = 1.0f / sum;
      #pragma unroll
      for (int t = 0; t < 8; t++) s[t][r] *= inv;
    }

    // PV in 4 k-quarters via per-wave P buffer [16][40]
    ushort_t* pw = p_s + wave*640;
    f32x4 po[2] = { f32x4{0.f,0.f,0.f,0.f}, f32x4{0.f,0.f,0.f,0.f} };
    #pragma unroll
    for (int q = 0; q < 4; q++){
      #pragma unroll
      for (int r = 0; r < 4; r++){
        #pragma unroll
        for (int t2 = 0; t2 < 2; t2++)
          pw[(lq*4 + r)*40 + t2*16 + l16] = f2bf(s[2*q + t2][r]);
      }
      bf16x8 ap = *reinterpret_cast<const bf16x8*>(&pw[l16*40 + lq*8]);
      #pragma unroll
      for (int ct = 0; ct < 2; ct++){
        bf16x8 bv = *reinterpret_cast<const bf16x8*>(&v_s[(ct*16 + l16)*136 + q*32 + lq*8]);
        po[ct] = mfma16(ap, bv, po[ct]);
      }
    }
    #pragma unroll
    for (int ct = 0; ct < 2; ct++){
      const int d = ct*16 + l16;
      if (d < HD){
        #pragma unroll
        for (int r = 0; r < 4; r++)
          ao_s[(wbase + lq*4 + r)*196 + h*HD + d] = f2bf(po[ct][r]);
      }
    }
  }

  // FC: per-wave rows only -> no barrier needed. B-fragments from L2-resident wfcT.
  f32x4 acc2[12];
  #pragma unroll
  for (int j = 0; j < 12; j++) acc2[j] = f32x4{0.f,0.f,0.f,0.f};
  #pragma unroll
  for (int ks = 0; ks < 6; ks++){
    const int kl = ks*32 + lq*8;
    bf16x8 af = *reinterpret_cast<const bf16x8*>(&ao_s[(wbase + l16)*196 + kl]);
    #pragma unroll
    for (int ct = 0; ct < 12; ct++){
      bf16x8 bw = *reinterpret_cast<const bf16x8*>(wfcT + (size_t)(ct*16 + l16)*KP + kl);
      acc2[ct] = mfma16(af, bw, acc2[ct]);
    }
  }
  #pragma unroll
  for (int ct = 0; ct < 12; ct++){
    const int col = ct*16 + l16;
    if (col < DIMX){
      const float bb = b_fc[col];
      #pragma unroll
      for (int r = 0; r < 4; r++){
        const int row = wbase + lq*4 + r;
        out[((size_t)b*NTOK + row)*DIMX + col] = acc2[ct][r] + bb;
      }
    }
  }
}

// ---------------- launch ----------------
extern "C" void kernel_launch(void* const* d_in, const int* in_sizes, int n_in,
                              void* d_out, int out_size, void* d_ws, size_t ws_size,
                              hipStream_t stream)
{
  const float* x      = (const float*)d_in[0];
  const float* w_qkv  = (const float*)d_in[1];
  const float* b_qkv  = (const float*)d_in[2];
  const float* w_fc   = (const float*)d_in[3];
  const float* b_fc   = (const float*)d_in[4];
  const float* rpt    = (const float*)d_in[5];
  const float* mask   = (const float*)d_in[6];
  const int*   rpi    = (const int*)d_in[7];
  float* out = (float*)d_out;

  char* ws = (char*)d_ws;
  // layout (bytes):
  //   0         wqkvT   576*192*2 = 221184
  //   221184    wfcT    192*192*2 = 73728
  //   294912    bias_p  64*6*8*64*32*2 = 12582912
  //   12877824  Qo      1024*6*128*32*2 = 50331648
  //   63209472  Ko      50331648
  //   113541120 Vo      50331648   -> total 163872768
  if (ws_size < (size_t)163872768) return;
  ushort_t* wqkvT  = (ushort_t*)(ws);
  ushort_t* wfcT   = (ushort_t*)(ws + 221184);
  ushort_t* bias_p = (ushort_t*)(ws + 294912);
  ushort_t* Qo     = (ushort_t*)(ws + 12877824);
  ushort_t* Ko     = (ushort_t*)(ws + 63209472);
  ushort_t* Vo     = (ushort_t*)(ws + 113541120);

  hipLaunchKernelGGL(prep_wqkv, dim3(NQKV), dim3(KP), 0, stream, w_qkv, wqkvT);
  hipLaunchKernelGGL(prep_wfc,  dim3(KP),   dim3(KP), 0, stream, w_fc, wfcT);
  hipLaunchKernelGGL(prep_bias, dim3(NWIN*NH*8), dim3(512), 0, stream, rpt, mask, rpi, bias_p);

  (void)hipFuncSetAttribute((const void*)qkv_kernel,
                            hipFuncAttributeMaxDynamicSharedMemorySize, 77824);
  hipLaunchKernelGGL(qkv_kernel, dim3(2048), dim3(512), 77824, stream,
                     x, wqkvT, b_qkv, Qo, Ko, Vo);

  (void)hipFuncSetAttribute((const void*)attn_kernel,
                            hipFuncAttributeMaxDynamicSharedMemorySize, 78336);
  hipLaunchKernelGGL(attn_kernel, dim3(1024), dim3(512), 78336, stream,
                     Qo, Ko, Vo, bias_p, wfcT, b_fc, out);
}